// Round 1
// 901.306 us; speedup vs baseline: 1.3390x; 1.3390x over previous
//
#include <hip/hip_runtime.h>

#define NN 100000   // nodes
#define NE 400000   // edges per relation
#define NR 8        // relations
#define DD 128      // feature dim
#define NBK 391     // buckets per relation: ceil(NN/256)
#define BCAP 1536   // capacity per bucket region (mean 1024, +16 sigma)
#define P1B 32      // phase-1 blocks per relation
#define NNP 100096  // padded rows (tile over-read safety)

typedef unsigned short ushort_t;
using short8  = __attribute__((ext_vector_type(8))) short;
using f32x4   = __attribute__((ext_vector_type(4))) float;

__device__ __forceinline__ ushort_t f2bf(float f) {
  union { float f; unsigned u; } v; v.f = f;
  unsigned u = v.u;
  return (ushort_t)((u + 0x7FFFu + ((u >> 16) & 1u)) >> 16);  // RNE
}
__device__ __forceinline__ float bf2f(unsigned hs) {
  union { unsigned u; float f; } v; v.u = hs << 16;
  return v.f;
}

#define GLL16(gp, lp) __builtin_amdgcn_global_load_lds( \
    (const __attribute__((address_space(1))) unsigned*)(gp), \
    (__attribute__((address_space(3))) unsigned*)(lp), 16, 0, 0)

// ---------------- conversion ----------------
__global__ __launch_bounds__(256) void f32_to_bf16_kernel(const float* __restrict__ in,
                                                          ushort_t* __restrict__ out, int n4) {
  int t = blockIdx.x * 256 + threadIdx.x;
  if (t < n4) {
    float4 f = ((const float4*)in)[t];
    uint2 p;
    p.x = (unsigned)f2bf(f.x) | ((unsigned)f2bf(f.y) << 16);
    p.y = (unsigned)f2bf(f.z) | ((unsigned)f2bf(f.w) << 16);
    ((uint2*)out)[t] = p;
  }
}

// repack fc_src_w [3][8][128][128] f32 -> Wcat [3][128(o)][8(r)][128(d)] bf16
__global__ __launch_bounds__(256) void wcat_kernel(const float* __restrict__ in, unsigned* __restrict__ out) {
  int t = blockIdx.x * 256 + threadIdx.x;  // 3*8*128*64 threads, one per bf16 pair
  int d2 = t & 63;
  int o  = (t >> 6) & 127;
  int r  = (t >> 13) & 7;
  int l  = t >> 16;
  const float* p = in + ((((size_t)l * 8 + r) * 128 + o) * 128 + 2 * d2);
  unsigned v = (unsigned)f2bf(p[0]) | ((unsigned)f2bf(p[1]) << 16);
  out[(((size_t)l * 128 + o) * 8 + r) * 64 + d2] = v;
}

// ---------------- CSR build: phase 1 — bucket by dst>>8, LDS-staged 64B flushes ----------------
// entry pack: (src << 8) | (dst & 255)
__global__ __launch_bounds__(256) void bucket_kernel(const int* __restrict__ edge_dst,
                                                     const int* __restrict__ edge_src,
                                                     int* __restrict__ gcur, unsigned* __restrict__ E1) {
  __shared__ unsigned stage[NBK][32];
  __shared__ int lcnt[NBK];
  int r   = blockIdx.x >> 5;
  int blk = blockIdx.x & 31;
  int t = threadIdx.x;
  for (int i = t; i < NBK; i += 256) lcnt[i] = 0;
  __syncthreads();
  const int per = NE / P1B;          // 12500
  int e0 = blk * per, e1 = e0 + per;
  const int* ed = edge_dst + (size_t)r * NE;
  const int* es = edge_src + (size_t)r * NE;
  int* gc = gcur + r * NBK;
  unsigned* E1r = E1 + (size_t)r * NBK * BCAP;
  for (int base = e0; base < e1; base += 4096) {
    int lim = min(base + 4096, e1);
    for (int e = base + t; e < lim; e += 256) {
      int d = ed[e];
      unsigned val = ((unsigned)es[e] << 8) | (unsigned)(d & 255);
      int b = d >> 8;
      int slot = atomicAdd(&lcnt[b], 1);
      if (slot < 32) stage[b][slot] = val;
      else {  // rare overflow: direct spill
        int p = atomicAdd(&gc[b], 1);
        if (p < BCAP) E1r[(size_t)b * BCAP + p] = val;
      }
    }
    __syncthreads();
    for (int b = t; b < NBK; b += 256) {
      int c = lcnt[b]; if (c > 32) c = 32;
      int nf = c & ~15;               // flush multiples of 16 (64B)
      if (nf) {
        int p = atomicAdd(&gc[b], nf);
        for (int k = 0; k < nf; k++)
          if (p + k < BCAP) E1r[(size_t)b * BCAP + p + k] = stage[b][k];
        for (int k = nf; k < c; k++) stage[b][k - nf] = stage[b][k];
      }
      lcnt[b] = c - nf;
    }
    __syncthreads();
  }
  for (int b = t; b < NBK; b += 256) {
    int c = lcnt[b]; if (c > 32) c = 32;
    if (c) {
      int p = atomicAdd(&gc[b], c);
      for (int k = 0; k < c; k++)
        if (p + k < BCAP) E1r[(size_t)b * BCAP + p + k] = stage[b][k];
    }
  }
}

// ---------------- CSR build: scan bucket counts -> bucket base offsets ----------------
__global__ __launch_bounds__(256) void bscan_kernel(const int* __restrict__ gcur, int* __restrict__ bbase) {
  __shared__ int ps[256];
  int t = threadIdx.x;
  int vals[13];
  int s = 0;
#pragma unroll
  for (int i = 0; i < 13; i++) {
    int idx = t * 13 + i;
    int c = (idx < NR * NBK) ? min(gcur[idx], BCAP) : 0;
    vals[i] = s; s += c;
  }
  ps[t] = s;
  __syncthreads();
  for (int off = 1; off < 256; off <<= 1) {
    int x = (t >= off) ? ps[t - off] : 0;
    __syncthreads();
    ps[t] += x;
    __syncthreads();
  }
  int excl = ps[t] - s;
#pragma unroll
  for (int i = 0; i < 13; i++) {
    int idx = t * 13 + i;
    if (idx < NR * NBK) bbase[idx] = excl + vals[i];
  }
}

// ---------------- CSR build: phase 2 — per-bucket exact CSR ----------------
__global__ __launch_bounds__(256) void csr_kernel(const unsigned* __restrict__ E1, const int* __restrict__ gcur,
                                                  const int* __restrict__ bbase,
                                                  int* __restrict__ offs, int* __restrict__ srcs) {
  __shared__ unsigned ent[BCAP];
  __shared__ int cnt[256], pref[256], excl_s[256];
  int rb = blockIdx.x;                 // r*NBK + b
  int b = rb % NBK, r = rb / NBK;
  int t = threadIdx.x;
  int n = min(gcur[rb], BCAP);
  const unsigned* src = E1 + (size_t)rb * BCAP;
  for (int i = t; i < n; i += 256) ent[i] = src[i];
  cnt[t] = 0;
  __syncthreads();
  for (int i = t; i < n; i += 256) atomicAdd(&cnt[ent[i] & 255], 1);
  __syncthreads();
  int v = cnt[t];
  pref[t] = v;
  __syncthreads();
  for (int off = 1; off < 256; off <<= 1) {
    int x = (t >= off) ? pref[t - off] : 0;
    __syncthreads();
    pref[t] += x;
    __syncthreads();
  }
  int excl = pref[t] - v;
  excl_s[t] = excl;
  int gb = bbase[rb];
  int d = b * 256 + t;
  if (d < NN) offs[(size_t)r * NN + d] = gb + excl;
  if (rb == NR * NBK - 1 && t == 0) offs[(size_t)NR * NN] = NR * NE;
  cnt[t] = 0;
  __syncthreads();
  for (int i = t; i < n; i += 256) {
    unsigned e = ent[i];
    int dl = e & 255;
    int p = atomicAdd(&cnt[dl], 1);
    srcs[gb + excl_s[dl] + p] = (int)(e >> 8);
  }
}

// ---------------- attention vectors for ALL layers -> bf16 UV table [3][16][128] ----------------
// row c<8: u_r = Wsrc_r^T al_r ; row 8+r: v_r = Wdst_r^T ar_r
__global__ __launch_bounds__(128) void uv_all_kernel(const float* __restrict__ Wsrc, const float* __restrict__ Wdst,
                                                     const float* __restrict__ al, const float* __restrict__ ar,
                                                     ushort_t* __restrict__ uvb) {
  int rl = blockIdx.x, j = threadIdx.x;   // rl = l*8 + r over 24
  int l = rl >> 3, r = rl & 7;
  const float* Ws = Wsrc + (size_t)rl * DD * DD;
  const float* Wd = Wdst + (size_t)rl * DD * DD;
  float su = 0.f, sv = 0.f;
  for (int i = 0; i < DD; i++) {
    su += al[rl * DD + i] * Ws[i * DD + j];
    sv += ar[rl * DD + i] * Wd[i * DD + j];
  }
  uvb[((size_t)l * 16 + r) * DD + j]     = f2bf(su);
  uvb[((size_t)l * 16 + 8 + r) * DD + j] = f2bf(sv);
}

// ---------------- elr via MFMA: ELR[16][NN] = (xb @ UV^T)^T ----------------
__global__ __launch_bounds__(256) void elr_kernel(const ushort_t* __restrict__ xb,
                                                  const ushort_t* __restrict__ uvb,
                                                  float* __restrict__ elr) {
  int t = threadIdx.x;
  int lane = t & 63, wave = t >> 6;
  int m16 = lane & 15, kq = lane >> 4;
  int n0 = blockIdx.x * 64 + wave * 16;
  const short8* Ag = (const short8*)xb;    // 16 chunks per row
  const short8* Bg = (const short8*)uvb;   // 16 chunks per row
  int bbase = m16 * 16 + kq;
  short8 b0 = Bg[bbase + 0];
  short8 b1 = Bg[bbase + 4];
  short8 b2 = Bg[bbase + 8];
  short8 b3 = Bg[bbase + 12];
  size_t abase = (size_t)(n0 + m16) * 16 + kq;
  short8 a0 = Ag[abase + 0];
  short8 a1 = Ag[abase + 4];
  short8 a2 = Ag[abase + 8];
  short8 a3 = Ag[abase + 12];
  f32x4 acc = (f32x4)(0.f);
  acc = __builtin_amdgcn_mfma_f32_16x16x32_bf16(a0, b0, acc, 0, 0, 0);
  acc = __builtin_amdgcn_mfma_f32_16x16x32_bf16(a1, b1, acc, 0, 0, 0);
  acc = __builtin_amdgcn_mfma_f32_16x16x32_bf16(a2, b2, acc, 0, 0, 0);
  acc = __builtin_amdgcn_mfma_f32_16x16x32_bf16(a3, b3, acc, 0, 0, 0);
  // C/D: col = m16 (ELR row), tile row = kq*4 + i (node)
#pragma unroll
  for (int i = 0; i < 4; i++) {
    int n = n0 + kq * 4 + i;
    if (n < NN) elr[(size_t)m16 * NN + n] = acc[i];
  }
}

// ---------------- FUSED: per-relation edge-softmax aggregation + MFMA GEMM ----------------
// Per block: 128 output rows (nodes) x 128 cols. 8 phases (one per relation):
//   phase kc: stage W block kc via global_load_lds (async, hides under gather),
//             aggregate AGG tile [128 nodes][128 feats] for relation kc into
//             swizzled LDS sA (32 groups of 16 lanes; 4-edge-unrolled gather loop
//             for MLP), barrier, 32 MFMA per wave accumulating into acc[8].
// Eliminates the 2x205 MB/layer AGG round trip entirely.
#define ACC8(P, W) { a0 += (W) * bf2f((P).x & 0xffffu); a1 += (W) * bf2f((P).x >> 16); \
                     a2 += (W) * bf2f((P).y & 0xffffu); a3 += (W) * bf2f((P).y >> 16); \
                     a4 += (W) * bf2f((P).z & 0xffffu); a5 += (W) * bf2f((P).z >> 16); \
                     a6 += (W) * bf2f((P).w & 0xffffu); a7 += (W) * bf2f((P).w >> 16); }

__global__ __launch_bounds__(512, 4) void agg_gemm_kernel(
    const int* __restrict__ srcs, const int* __restrict__ offs,
    const float* __restrict__ el, const float* __restrict__ er,
    const ushort_t* __restrict__ xin, const ushort_t* __restrict__ Wl,
    const float* __restrict__ bias, ushort_t* __restrict__ xout,
    float* __restrict__ dout, int relu, int last) {
  __shared__ uint4 sA[2048];   // 128 rows x 16 chunks, XOR-swizzled
  __shared__ uint4 sW[2048];   // 128 cols x 16 chunks, XOR-swizzled
  __shared__ float sB[DD];
  int t = threadIdx.x;
  if (t < DD) sB[t] = bias[t];
  int lane = t & 63, wave = t >> 6;
  int m16 = lane & 15, kq = lane >> 4;
  int group = t >> 4, lane16 = t & 15;   // 32 groups of 16 lanes
  int row0 = blockIdx.x * 128;
  const uint4* Wg = (const uint4*)Wl;
  const uint4* xg = (const uint4*)xin;
  f32x4 acc[8];
#pragma unroll
  for (int nt = 0; nt < 8; nt++) acc[nt] = (f32x4)(0.f);

#pragma unroll 1
  for (int kc = 0; kc < NR; kc++) {
    __syncthreads();   // previous phase's MFMA done reading sA/sW
    // async-stage W block kc: LDS slot (r,c) holds global chunk (r, kc*16 + (c^(r&15)))
#pragma unroll
    for (int i = 0; i < 4; i++) {
      int g = t + 512 * i;
      int r = g >> 4, c = g & 15;
      int cp = c ^ (r & 15);
      GLL16(Wg + (size_t)r * (NR * 16) + kc * 16 + cp, sW + g);
    }
    const float* elv = el + (size_t)kc * NN;
    const float* erv = er + (size_t)kc * NN;
    const int*   ofv = offs + (size_t)kc * NN;
#pragma unroll 1
    for (int sub = 0; sub < 4; sub++) {
      int rr = sub * 32 + group;         // node row within tile
      int n = row0 + rr;
      float a0 = 0.f, a1 = 0.f, a2 = 0.f, a3 = 0.f,
            a4 = 0.f, a5 = 0.f, a6 = 0.f, a7 = 0.f;
      if (n < NN) {
        int k0 = ofv[n], k1 = ofv[n + 1];
        if (k1 > k0) {
          float erd = erv[n];
          float denom = 0.f;
          for (int e = k0; e < k1; e += 4) {   // 4-wide: 4 gathers + 4 exp in flight
            int rem = k1 - e;
            int s0 = srcs[e];
            int s1 = srcs[rem > 1 ? e + 1 : e];
            int s2 = srcs[rem > 2 ? e + 2 : e];
            int s3 = srcs[rem > 3 ? e + 3 : e];
            uint4 p0 = xg[(unsigned)s0 * 16u + (unsigned)lane16];
            uint4 p1 = xg[(unsigned)s1 * 16u + (unsigned)lane16];
            uint4 p2 = xg[(unsigned)s2 * 16u + (unsigned)lane16];
            uint4 p3 = xg[(unsigned)s3 * 16u + (unsigned)lane16];
            float x0 = elv[s0] + erd, x1 = elv[s1] + erd;
            float x2 = elv[s2] + erd, x3 = elv[s3] + erd;
            x0 = fmaxf(x0, 0.2f * x0);   // leaky_relu(x,0.2) == max(x, 0.2x)
            x1 = fmaxf(x1, 0.2f * x1);
            x2 = fmaxf(x2, 0.2f * x2);
            x3 = fmaxf(x3, 0.2f * x3);
            float w0 = __expf(x0);
            float w1 = (rem > 1) ? __expf(x1) : 0.f;
            float w2 = (rem > 2) ? __expf(x2) : 0.f;
            float w3 = (rem > 3) ? __expf(x3) : 0.f;
            denom += (w0 + w1) + (w2 + w3);
            ACC8(p0, w0); ACC8(p1, w1); ACC8(p2, w2); ACC8(p3, w3);
          }
          float inv = 1.f / denom;
          a0 *= inv; a1 *= inv; a2 *= inv; a3 *= inv;
          a4 *= inv; a5 *= inv; a6 *= inv; a7 *= inv;
        }
      }
      uint4 ov;
      ov.x = (unsigned)f2bf(a0) | ((unsigned)f2bf(a1) << 16);
      ov.y = (unsigned)f2bf(a2) | ((unsigned)f2bf(a3) << 16);
      ov.z = (unsigned)f2bf(a4) | ((unsigned)f2bf(a5) << 16);
      ov.w = (unsigned)f2bf(a6) | ((unsigned)f2bf(a7) << 16);
      sA[rr * 16 + (lane16 ^ (rr & 15))] = ov;   // same swizzle the MFMA read expects
    }
    __syncthreads();   // sA written; barrier drains vmcnt -> sW loaded
    int ra0 = wave * 16 + m16;
#pragma unroll
    for (int s = 0; s < 4; s++) {
      int cs = (s * 4 + kq) ^ m16;
      short8 af = *reinterpret_cast<const short8*>(sA + (ra0 * 16 + cs));
#pragma unroll
      for (int nt = 0; nt < 8; nt++) {
        short8 bf = *reinterpret_cast<const short8*>(sW + ((nt * 16 + m16) * 16 + cs));
        acc[nt] = __builtin_amdgcn_mfma_f32_16x16x32_bf16(af, bf, acc[nt], 0, 0, 0);
      }
    }
  }
  // epilogue: C/D col = m16 + 16*nt, row = wave*16 + kq*4 + i
#pragma unroll
  for (int i = 0; i < 4; i++) {
    int row = row0 + wave * 16 + kq * 4 + i;
    if (row < NN) {
#pragma unroll
      for (int nt = 0; nt < 8; nt++) {
        float vv = acc[nt][i] + sB[m16 + 16 * nt];
        if (relu) vv = fmaxf(vv, 0.f);
        if (last) dout[(size_t)row * DD + m16 + 16 * nt] = vv;
        else      xout[(size_t)row * DD + m16 + 16 * nt] = f2bf(vv);
      }
    }
  }
}

extern "C" void kernel_launch(void* const* d_in, const int* in_sizes, int n_in,
                              void* d_out, int out_size, void* d_ws, size_t ws_size,
                              hipStream_t stream) {
  const float* h        = (const float*)d_in[0];
  const int*   edge_src = (const int*)d_in[1];
  const int*   edge_dst = (const int*)d_in[2];
  const float* fc_src_w = (const float*)d_in[3];
  const float* fc_dst_w = (const float*)d_in[4];
  const float* attn_l   = (const float*)d_in[5];
  const float* attn_r   = (const float*)d_in[6];
  const float* h_bias   = (const float*)d_in[7];
  float* dout = (float*)d_out;
  (void)in_sizes; (void)n_in; (void)out_size; (void)ws_size;

  char* base = (char*)d_ws;
  size_t off = 0;
  auto alloc = [&](size_t bytes) -> void* {
    void* p = base + off;
    off += (bytes + 255) & ~(size_t)255;
    return p;
  };
  ushort_t* xb0   = (ushort_t*)alloc((size_t)NNP * DD * 2);   // layer ping buffer
  ushort_t* xb1   = (ushort_t*)alloc((size_t)NNP * DD * 2);   // layer pong buffer
  float*    ELR   = (float*)   alloc((size_t)16 * NN * 4);    // rows 0-7: el_r, 8-15: er_r
  ushort_t* uvb   = (ushort_t*)alloc((size_t)3 * 16 * DD * 2);
  ushort_t* Wcat  = (ushort_t*)alloc((size_t)3 * DD * NR * DD * 2);
  int*      offs  = (int*)     alloc(((size_t)NR * NN + 1) * 4);
  unsigned* E1    = (unsigned*)alloc((size_t)NR * NBK * BCAP * 4);
  int*      gcur  = (int*)     alloc((size_t)NR * NBK * 4);
  int*      bbase = (int*)     alloc((size_t)NR * NBK * 4);
  int*      srcs  = (int*)     alloc((size_t)NR * NE * 4);

  // ---- CSR build ----
  (void)hipMemsetAsync(gcur, 0, (size_t)NR * NBK * 4, stream);
  // zero pad rows of ping/pong buffers (elr_kernel over-reads up to NNP)
  (void)hipMemsetAsync(xb0 + (size_t)NN * DD, 0, (size_t)(NNP - NN) * DD * 2, stream);
  (void)hipMemsetAsync(xb1 + (size_t)NN * DD, 0, (size_t)(NNP - NN) * DD * 2, stream);
  bucket_kernel<<<NR * P1B, 256, 0, stream>>>(edge_dst, edge_src, gcur, E1);
  bscan_kernel<<<1, 256, 0, stream>>>(gcur, bbase);
  csr_kernel<<<NR * NBK, 256, 0, stream>>>(E1, gcur, bbase, offs, srcs);

  f32_to_bf16_kernel<<<(NN * DD / 4 + 255) / 256, 256, 0, stream>>>(h, xb0, NN * DD / 4);
  wcat_kernel<<<3 * NR * DD * (DD / 2) / 256, 256, 0, stream>>>(fc_src_w, (unsigned*)Wcat);
  uv_all_kernel<<<3 * NR, 128, 0, stream>>>(fc_src_w, fc_dst_w, attn_l, attn_r, uvb);

  const float* el = ELR;
  const float* er = ELR + (size_t)8 * NN;
  for (int l = 0; l < 3; l++) {
    ushort_t* xin  = (l & 1) ? xb1 : xb0;
    ushort_t* xout = (l & 1) ? xb0 : xb1;
    elr_kernel<<<(NN + 63) / 64, 256, 0, stream>>>(xin, uvb + (size_t)l * 16 * DD, ELR);
    agg_gemm_kernel<<<(NN + 127) / 128, 512, 0, stream>>>(
        srcs, offs, el, er, xin, Wcat + (size_t)l * DD * NR * DD,
        h_bias + (size_t)l * DD, xout, dout, (l < 2) ? 1 : 0, (l == 2) ? 1 : 0);
  }
}